// Round 9
// baseline (178.720 us; speedup 1.0000x reference)
//
#include <hip/hip_runtime.h>

// B=2, T=2048, D_MODEL=1024, H=16, Dh=64. Inputs fp32, output fp32.
// R9: - attn: 512-thr blocks (8 waves x 16q = 128q strips), grid 256 with
//       bh%8 XCD affinity (4 heads -> 4MB K/V per XCD L2); pairs (p,15-p).
//     - gemm: double-buffered BK=64 staging, one barrier per iter.

using bf16x8  = __attribute__((ext_vector_type(8))) __bf16;
using floatx4 = __attribute__((ext_vector_type(4))) float;

#define T_SEQ   2048
#define D_MODEL 1024
#define N_HEADS 16
#define D_HEAD  64
#define BATCH   2
#define M_TOT   4096
#define N_TOT   3072
#define PLANE   (T_SEQ * D_HEAD)
#define NX      (M_TOT * D_MODEL)
#define NWSEG   (D_MODEL * D_MODEL)
#define QSCALE  0.18033688f   // 0.125 * log2(e)
#define SM_BIAS 24.0f

__device__ __forceinline__ unsigned short f32_to_bf16(float f) {
  unsigned int u = __float_as_uint(f);
  u += 0x7fffu + ((u >> 16) & 1u);
  return (unsigned short)(u >> 16);
}
__device__ __forceinline__ unsigned int pack2_bf16(float a, float b) {
  unsigned int ua = __float_as_uint(a) + 0x8000u;
  unsigned int ub = __float_as_uint(b) + 0x8000u;
  return __builtin_amdgcn_perm(ub, ua, 0x07060302);
}
__device__ __forceinline__ void async_cp16(void* lds, const void* gptr) {
  __builtin_amdgcn_global_load_lds(
      (const __attribute__((address_space(1))) unsigned int*)gptr,
      (__attribute__((address_space(3))) unsigned int*)lds, 16, 0, 0);
}

// ---------------------------------------------------------------------------
// K0: fp32 -> bf16 cvt.
// ---------------------------------------------------------------------------
__global__ __launch_bounds__(256) void cvt_kernel(
    const float* __restrict__ X,  const float* __restrict__ Wq,
    const float* __restrict__ Wk, const float* __restrict__ Wv,
    unsigned short* __restrict__ Xb, unsigned short* __restrict__ Wb)
{
  const size_t i = ((size_t)blockIdx.x * 256 + threadIdx.x) * 8;
  const float* src;
  unsigned short* dst;
  if (i < NX) { src = X + i; dst = Xb + i; }
  else {
    const size_t r = i - NX;
    const int w = (int)(r >> 20);
    const size_t o = r & (NWSEG - 1);
    src = ((w == 0) ? Wq : (w == 1) ? Wk : Wv) + o;
    dst = Wb + r;
  }
  float4 f0 = *(const float4*)src;
  float4 f1 = *(const float4*)(src + 4);
  uint4 out;
  out.x = pack2_bf16(f0.x, f0.y);
  out.y = pack2_bf16(f0.z, f0.w);
  out.z = pack2_bf16(f1.x, f1.y);
  out.w = pack2_bf16(f1.z, f1.w);
  *(uint4*)dst = out;
}

// ---------------------------------------------------------------------------
// K1: bf16 GEMM, 128x128 tile, BK=64 double-buffered (1 barrier/iter).
// ---------------------------------------------------------------------------
__global__ __launch_bounds__(256) void gemm_qkv(
    const unsigned short* __restrict__ Xb,
    const unsigned short* __restrict__ Wb,
    unsigned short* __restrict__ Qb,
    unsigned short* __restrict__ Kb,
    unsigned short* __restrict__ VTb)
{
  __shared__ unsigned short Als[2][128 * 64];   // 2 x 16 KB
  __shared__ unsigned short Bls[2][128 * 64];

  const int tid  = threadIdx.x;
  const int lane = tid & 63;
  const int wave = tid >> 6;
  const int l15  = lane & 15;
  const int quad = lane >> 4;
  const int wm   = wave >> 1, wn = wave & 1;

  const int n_blk = blockIdx.x * 128;
  const int m_blk = blockIdx.y * 128;

  const int swz = (((tid >> 3) ^ tid) & 7) * 8;
  const unsigned short* Ag = Xb + (size_t)(m_blk + (tid >> 3)) * D_MODEL + swz;
  const unsigned short* Bg = Wb + (size_t)(n_blk + (tid >> 3)) * D_MODEL + swz;

  floatx4 acc[4][4] = {};

  // prologue: stage k-slice 0 into buf 0
#pragma unroll
  for (int p = 0; p < 4; p++) {
    async_cp16((char*)Als[0] + wave * 1024 + p * 4096, Ag + (size_t)p * 32 * D_MODEL);
    async_cp16((char*)Bls[0] + wave * 1024 + p * 4096, Bg + (size_t)p * 32 * D_MODEL);
  }

  for (int it = 0; it < 16; it++) {
    __syncthreads();                       // drains stage(it); prior reads done
    if (it < 15) {
      const int k1 = (it + 1) * 64;
      char* al = (char*)Als[(it + 1) & 1] + wave * 1024;
      char* bl = (char*)Bls[(it + 1) & 1] + wave * 1024;
#pragma unroll
      for (int p = 0; p < 4; p++) {
        async_cp16(al + p * 4096, Ag + (size_t)p * 32 * D_MODEL + k1);
        async_cp16(bl + p * 4096, Bg + (size_t)p * 32 * D_MODEL + k1);
      }
    }
    const char* A = (const char*)Als[it & 1];
    const char* B = (const char*)Bls[it & 1];
#pragma unroll
    for (int ks = 0; ks < 2; ks++) {
      bf16x8 a[4], b[4];
#pragma unroll
      for (int i = 0; i < 4; i++) {
        const int sa = ((ks * 4 + quad) ^ (l15 & 7)) * 16;
        a[i] = *(const bf16x8*)(A + (wm * 64 + 16 * i + l15) * 128 + sa);
        b[i] = *(const bf16x8*)(B + (wn * 64 + 16 * i + l15) * 128 + sa);
      }
#pragma unroll
      for (int mi = 0; mi < 4; mi++)
#pragma unroll
        for (int ni = 0; ni < 4; ni++)
          acc[mi][ni] = __builtin_amdgcn_mfma_f32_16x16x32_bf16(a[mi], b[ni], acc[mi][ni], 0, 0, 0);
    }
  }

  // epilogue: stage C tile in LDS (reuse Als region), coalesced copy-out
  __syncthreads();
  char* ep = (char*)Als + wave * 8192;
  const int w_sel  = n_blk >> 10;
  const int m_base = m_blk + wm * 64;
  const int n_base = n_blk + wn * 64;
  const int h      = (n_base & 1023) >> 6;
  const float csc  = (w_sel == 0) ? QSCALE : 1.0f;

  if (w_sel < 2) {
#pragma unroll
    for (int mi = 0; mi < 4; mi++)
#pragma unroll
      for (int ni = 0; ni < 4; ni++)
#pragma unroll
        for (int r = 0; r < 4; r++) {
          const int row  = 16 * mi + quad * 4 + r;
          const int colb = (16 * ni + l15) * 2;
          const int phys = ((colb >> 4) ^ (row & 7)) * 16;
          *(unsigned short*)(ep + row * 128 + phys + (colb & 15)) =
              f32_to_bf16(acc[mi][ni][r] * csc);
        }
  } else {
#pragma unroll
    for (int mi = 0; mi < 4; mi++)
#pragma unroll
      for (int ni = 0; ni < 4; ni++)
#pragma unroll
        for (int r = 0; r < 4; r++) {
          const int row  = 16 * ni + l15;
          const int colb = (16 * mi + quad * 4 + r) * 2;
          const int phys = ((colb >> 4) ^ (row & 7)) * 16;
          *(unsigned short*)(ep + row * 128 + phys + (colb & 15)) =
              f32_to_bf16(acc[mi][ni][r]);
        }
  }
  asm volatile("s_waitcnt lgkmcnt(0)" ::: "memory");

#pragma unroll
  for (int pass = 0; pass < 8; pass++) {
    const int row  = pass * 8 + (lane >> 3);
    const int phys = ((lane & 7) ^ (row & 7)) * 16;
    uint4 v = *(const uint4*)(ep + row * 128 + phys);
    if (w_sel < 2) {
      const int m  = m_base + row;
      const int bb = m >> 11;
      const int t  = m & (T_SEQ - 1);
      unsigned short* dst = ((w_sel == 0) ? Qb : Kb) +
          ((size_t)(bb * N_HEADS + h) * T_SEQ + t) * D_HEAD + (lane & 7) * 8;
      *(uint4*)dst = v;
    } else {
      const int bb = m_base >> 11;
      unsigned short* dst = VTb +
          ((size_t)(bb * N_HEADS + h) * D_HEAD + row) * T_SEQ + (m_base & (T_SEQ - 1)) + (lane & 7) * 8;
      *(uint4*)dst = v;
    }
  }
}

// ---------------------------------------------------------------------------
// K2: causal flash attention. Grid 256 = 8 pairs x 32 bh (bh inner -> XCD
// affinity bh%8). Block 512 = 8 waves x 16 queries = 128-query strips;
// pairs (p, 15-p): 34 uniform 64-key chunks. K/V double-buffered.
// ---------------------------------------------------------------------------
__global__ __launch_bounds__(512) void attn_kernel(
    const unsigned short* __restrict__ Qb,   // pre-scaled by QSCALE
    const unsigned short* __restrict__ Kb,
    const unsigned short* __restrict__ VTb,
    float* __restrict__ Out)
{
  __shared__ unsigned short Ks[2][64 * 64];     // [key][d], swizzled
  __shared__ unsigned short Vs[2][64 * 64];     // [d][key], swizzled
  __shared__ unsigned short Ps[8][16 * 64];

  const int tid  = threadIdx.x;
  const int lane = tid & 63;
  const int wave = tid >> 6;
  const int l15  = lane & 15;
  const int quad = lane >> 4;

  const int bh   = blockIdx.x & 31;   // inner -> XCD = bh % 8
  const int pair = blockIdx.x >> 5;   // 0..7

  const unsigned short* Qp = Qb  + (size_t)bh * PLANE;
  const unsigned short* Kp = Kb  + (size_t)bh * PLANE;
  const unsigned short* Vp = VTb + (size_t)bh * PLANE;

  const int swz = (((tid >> 3) ^ tid) & 7) * 8;
  const unsigned short* Kg = Kp + (size_t)(tid >> 3) * D_HEAD + swz;   // 64 key-rows
  const unsigned short* Vg = Vp + (size_t)(tid >> 3) * T_SEQ + swz;    // 64 d-rows
  unsigned short* myp = Ps[wave];
  const int b = bh >> 4, h = bh & 15;

  for (int ph = 0; ph < 2; ph++) {
    const int strip = ph ? (15 - pair) : pair;
    const int q0w   = strip * 128 + wave * 16;
    const int nch   = 2 * strip + 2;

    bf16x8 aq[2];
#pragma unroll
    for (int s = 0; s < 2; s++)
      aq[s] = *(const bf16x8*)(Qp + (size_t)(q0w + l15) * D_HEAD + 32 * s + quad * 8);

    float l_acc[4] = {};
    floatx4 o[4] = {};

    __syncthreads();   // protect buf0 from previous phase readers
    async_cp16((char*)Ks[0] + wave * 1024, Kg);
    async_cp16((char*)Vs[0] + wave * 1024, Vg);

    for (int jc = 0; jc < nch; jc++) {
      __syncthreads();
      if (jc + 1 < nch) {
        const int j1 = (jc + 1) * 64;
        async_cp16((char*)Ks[(jc + 1) & 1] + wave * 1024, Kg + (size_t)j1 * D_HEAD);
        async_cp16((char*)Vs[(jc + 1) & 1] + wave * 1024, Vg + j1);
      }
      const char* Ksb = (const char*)Ks[jc & 1];
      const char* Vsb = (const char*)Vs[jc & 1];

      // S = Q K^T (exp2 domain)
      floatx4 s[4] = {};
#pragma unroll
      for (int t = 0; t < 4; t++)
#pragma unroll
        for (int ss = 0; ss < 2; ss++) {
          const int sa = ((ss * 4 + quad) ^ (l15 & 7)) * 16;
          bf16x8 bk = *(const bf16x8*)(Ksb + (16 * t + l15) * 128 + sa);
          s[t] = __builtin_amdgcn_mfma_f32_16x16x32_bf16(aq[ss], bk, s[t], 0, 0, 0);
        }

      if (64 * jc + 63 > q0w) {   // chunk touches/exceeds the diagonal
        const int j0 = jc * 64;
#pragma unroll
        for (int t = 0; t < 4; t++) {
          const int kk = j0 + 16 * t + l15;
#pragma unroll
          for (int r = 0; r < 4; r++)
            if (kk > q0w + quad * 4 + r) s[t][r] = -INFINITY;
        }
      }

      // fixed-bias softmax
#pragma unroll
      for (int t = 0; t < 4; t++)
#pragma unroll
        for (int r = 0; r < 4; r++)
          s[t][r] = exp2f(s[t][r] - SM_BIAS);
#pragma unroll
      for (int r = 0; r < 4; r++)
        l_acc[r] += (s[0][r] + s[1][r]) + (s[2][r] + s[3][r]);

      // P write (swizzled) for A-operand readback
#pragma unroll
      for (int t = 0; t < 4; t++)
#pragma unroll
        for (int r = 0; r < 4; r++) {
          const int row  = quad * 4 + r;
          const int phys = ((2 * t + (l15 >> 3)) ^ (row & 7)) * 16;
          *(unsigned short*)((char*)myp + row * 128 + phys + (l15 & 7) * 2) =
              f32_to_bf16(s[t][r]);
        }
      asm volatile("s_waitcnt lgkmcnt(0)" ::: "memory");

      // O += P @ V
#pragma unroll
      for (int ks = 0; ks < 2; ks++) {
        const int pa = ((ks * 4 + quad) ^ (l15 & 7)) * 16;
        bf16x8 ap = *(const bf16x8*)((char*)myp + l15 * 128 + pa);
#pragma unroll
        for (int n = 0; n < 4; n++) {
          const int sa = ((ks * 4 + quad) ^ (l15 & 7)) * 16;
          bf16x8 bv = *(const bf16x8*)(Vsb + (16 * n + l15) * 128 + sa);
          o[n] = __builtin_amdgcn_mfma_f32_16x16x32_bf16(ap, bv, o[n], 0, 0, 0);
        }
      }
    }

#pragma unroll
    for (int r = 0; r < 4; r++) {
#pragma unroll
      for (int d = 1; d < 16; d <<= 1) l_acc[r] += __shfl_xor(l_acc[r], d);
    }

#pragma unroll
    for (int r = 0; r < 4; r++) {
      const float inv_l = 1.0f / l_acc[r];
      const int t = q0w + quad * 4 + r;
#pragma unroll
      for (int n = 0; n < 4; n++)
        Out[(size_t)(b * T_SEQ + t) * D_MODEL + h * D_HEAD + 16 * n + l15] = o[n][r] * inv_l;
    }
  }
}

// ---------------------------------------------------------------------------
extern "C" void kernel_launch(void* const* d_in, const int* in_sizes, int n_in,
                              void* d_out, int out_size, void* d_ws, size_t ws_size,
                              hipStream_t stream) {
  const float* X  = (const float*)d_in[0];
  const float* Wq = (const float*)d_in[1];
  const float* Wk = (const float*)d_in[2];
  const float* Wv = (const float*)d_in[3];

  unsigned short* Qb = (unsigned short*)d_ws;
  unsigned short* Kb = Qb + (size_t)BATCH * N_HEADS * T_SEQ * D_HEAD;
  unsigned short* VT = Kb + (size_t)BATCH * N_HEADS * T_SEQ * D_HEAD;

  unsigned short* Xb = (unsigned short*)d_out;   // scratch, overwritten by attn
  unsigned short* Wb = Xb + (size_t)NX;

  cvt_kernel<<<3584, 256, 0, stream>>>(X, Wq, Wk, Wv, Xb, Wb);

  dim3 g1(N_TOT / 128, M_TOT / 128);
  gemm_qkv<<<g1, 256, 0, stream>>>(Xb, Wb, Qb, Kb, VT);

  attn_kernel<<<256, 512, 0, stream>>>(Qb, Kb, VT, (float*)d_out);
}

// Round 10
// 166.962 us; speedup vs baseline: 1.0704x; 1.0704x over previous
//
#include <hip/hip_runtime.h>

// B=2, T=2048, D_MODEL=1024, H=16, Dh=64. Inputs fp32, output fp32.
// R10: revert R9's gemm dbuf (m132 failure mode: 64KB LDS halved residency);
//      gemm = R8 single-buffer 32KB. attn = R8 kernel with bh-INNER grid
//      (XCD = bh%8 -> 2MB K/V per XCD L2 instead of 24MB streamed per XCD).

using bf16x8  = __attribute__((ext_vector_type(8))) __bf16;
using floatx4 = __attribute__((ext_vector_type(4))) float;

#define T_SEQ   2048
#define D_MODEL 1024
#define N_HEADS 16
#define D_HEAD  64
#define BATCH   2
#define M_TOT   4096
#define N_TOT   3072
#define PLANE   (T_SEQ * D_HEAD)
#define NX      (M_TOT * D_MODEL)
#define NWSEG   (D_MODEL * D_MODEL)
#define QSCALE  0.18033688f   // 0.125 * log2(e)
#define SM_BIAS 24.0f

__device__ __forceinline__ unsigned short f32_to_bf16(float f) {
  unsigned int u = __float_as_uint(f);
  u += 0x7fffu + ((u >> 16) & 1u);
  return (unsigned short)(u >> 16);
}
__device__ __forceinline__ unsigned int pack2_bf16(float a, float b) {
  unsigned int ua = __float_as_uint(a) + 0x8000u;
  unsigned int ub = __float_as_uint(b) + 0x8000u;
  return __builtin_amdgcn_perm(ub, ua, 0x07060302);
}
__device__ __forceinline__ void async_cp16(void* lds, const void* gptr) {
  __builtin_amdgcn_global_load_lds(
      (const __attribute__((address_space(1))) unsigned int*)gptr,
      (__attribute__((address_space(3))) unsigned int*)lds, 16, 0, 0);
}

// ---------------------------------------------------------------------------
// K0: fp32 -> bf16 cvt.
// ---------------------------------------------------------------------------
__global__ __launch_bounds__(256) void cvt_kernel(
    const float* __restrict__ X,  const float* __restrict__ Wq,
    const float* __restrict__ Wk, const float* __restrict__ Wv,
    unsigned short* __restrict__ Xb, unsigned short* __restrict__ Wb)
{
  const size_t i = ((size_t)blockIdx.x * 256 + threadIdx.x) * 8;
  const float* src;
  unsigned short* dst;
  if (i < NX) { src = X + i; dst = Xb + i; }
  else {
    const size_t r = i - NX;
    const int w = (int)(r >> 20);
    const size_t o = r & (NWSEG - 1);
    src = ((w == 0) ? Wq : (w == 1) ? Wk : Wv) + o;
    dst = Wb + r;
  }
  float4 f0 = *(const float4*)src;
  float4 f1 = *(const float4*)(src + 4);
  uint4 out;
  out.x = pack2_bf16(f0.x, f0.y);
  out.y = pack2_bf16(f0.z, f0.w);
  out.z = pack2_bf16(f1.x, f1.y);
  out.w = pack2_bf16(f1.z, f1.w);
  *(uint4*)dst = out;
}

// ---------------------------------------------------------------------------
// K1: bf16 GEMM C[4096x3072] = Xb @ Wb^T. Grid (24,32), block 256. BK=64.
// Single-buffered 32KB LDS (5 blocks/CU capacity -> cross-block overlap).
// ---------------------------------------------------------------------------
__global__ __launch_bounds__(256) void gemm_qkv(
    const unsigned short* __restrict__ Xb,
    const unsigned short* __restrict__ Wb,
    unsigned short* __restrict__ Qb,         // [B][H][T][64] * QSCALE
    unsigned short* __restrict__ Kb,         // [B][H][T][64]
    unsigned short* __restrict__ VTb)        // [B][H][64][T]
{
  __shared__ unsigned short Als[128 * 64];
  __shared__ unsigned short Bls[128 * 64];

  const int tid  = threadIdx.x;
  const int lane = tid & 63;
  const int wave = tid >> 6;
  const int l15  = lane & 15;
  const int quad = lane >> 4;
  const int wm   = wave >> 1, wn = wave & 1;

  const int n_blk = blockIdx.x * 128;
  const int m_blk = blockIdx.y * 128;

  const int swz = (((tid >> 3) ^ tid) & 7) * 8;
  const unsigned short* Ag = Xb + (size_t)(m_blk + (tid >> 3)) * D_MODEL + swz;
  const unsigned short* Bg = Wb + (size_t)(n_blk + (tid >> 3)) * D_MODEL + swz;
  char* Alds = (char*)Als + wave * 1024;
  char* Blds = (char*)Bls + wave * 1024;

  floatx4 acc[4][4] = {};

  for (int k0 = 0; k0 < D_MODEL; k0 += 64) {
    __syncthreads();
#pragma unroll
    for (int p = 0; p < 4; p++) {
      async_cp16(Alds + p * 4096, Ag + (size_t)p * 32 * D_MODEL + k0);
      async_cp16(Blds + p * 4096, Bg + (size_t)p * 32 * D_MODEL + k0);
    }
    __syncthreads();

#pragma unroll
    for (int ks = 0; ks < 2; ks++) {
      bf16x8 a[4], b[4];
#pragma unroll
      for (int i = 0; i < 4; i++) {
        const int sa = ((ks * 4 + quad) ^ (l15 & 7)) * 16;
        a[i] = *(const bf16x8*)((char*)Als + (wm * 64 + 16 * i + l15) * 128 + sa);
        b[i] = *(const bf16x8*)((char*)Bls + (wn * 64 + 16 * i + l15) * 128 + sa);
      }
#pragma unroll
      for (int mi = 0; mi < 4; mi++)
#pragma unroll
        for (int ni = 0; ni < 4; ni++)
          acc[mi][ni] = __builtin_amdgcn_mfma_f32_16x16x32_bf16(a[mi], b[ni], acc[mi][ni], 0, 0, 0);
    }
  }

  // epilogue: stage 64x64 C tile in LDS (swizzled), coalesced copy-out
  __syncthreads();
  char* ep = (char*)Als + wave * 8192;
  const int w_sel  = n_blk >> 10;
  const int m_base = m_blk + wm * 64;
  const int n_base = n_blk + wn * 64;
  const int h      = (n_base & 1023) >> 6;
  const float csc  = (w_sel == 0) ? QSCALE : 1.0f;

  if (w_sel < 2) {
#pragma unroll
    for (int mi = 0; mi < 4; mi++)
#pragma unroll
      for (int ni = 0; ni < 4; ni++)
#pragma unroll
        for (int r = 0; r < 4; r++) {
          const int row  = 16 * mi + quad * 4 + r;
          const int colb = (16 * ni + l15) * 2;
          const int phys = ((colb >> 4) ^ (row & 7)) * 16;
          *(unsigned short*)(ep + row * 128 + phys + (colb & 15)) =
              f32_to_bf16(acc[mi][ni][r] * csc);
        }
  } else {
#pragma unroll
    for (int mi = 0; mi < 4; mi++)
#pragma unroll
      for (int ni = 0; ni < 4; ni++)
#pragma unroll
        for (int r = 0; r < 4; r++) {
          const int row  = 16 * ni + l15;
          const int colb = (16 * mi + quad * 4 + r) * 2;
          const int phys = ((colb >> 4) ^ (row & 7)) * 16;
          *(unsigned short*)(ep + row * 128 + phys + (colb & 15)) =
              f32_to_bf16(acc[mi][ni][r]);
        }
  }
  asm volatile("s_waitcnt lgkmcnt(0)" ::: "memory");

#pragma unroll
  for (int pass = 0; pass < 8; pass++) {
    const int row  = pass * 8 + (lane >> 3);
    const int phys = ((lane & 7) ^ (row & 7)) * 16;
    uint4 v = *(const uint4*)(ep + row * 128 + phys);
    if (w_sel < 2) {
      const int m  = m_base + row;
      const int bb = m >> 11;
      const int t  = m & (T_SEQ - 1);
      unsigned short* dst = ((w_sel == 0) ? Qb : Kb) +
          ((size_t)(bb * N_HEADS + h) * T_SEQ + t) * D_HEAD + (lane & 7) * 8;
      *(uint4*)dst = v;
    } else {
      const int bb = m_base >> 11;
      unsigned short* dst = VTb +
          ((size_t)(bb * N_HEADS + h) * D_HEAD + row) * T_SEQ + (m_base & (T_SEQ - 1)) + (lane & 7) * 8;
      *(uint4*)dst = v;
    }
  }
}

// ---------------------------------------------------------------------------
// K2: causal flash attention, fixed-max softmax.
// Grid 512: bh = blockIdx & 31 (INNER -> XCD = bh%8), pair = blockIdx >> 5.
// Block 256 = 4 waves x 16q; strips (pair, 31-pair): 33 chunks uniform.
// ---------------------------------------------------------------------------
__global__ __launch_bounds__(256) void attn_kernel(
    const unsigned short* __restrict__ Qb,   // pre-scaled by QSCALE
    const unsigned short* __restrict__ Kb,
    const unsigned short* __restrict__ VTb,
    float* __restrict__ Out)
{
  __shared__ unsigned short Ks[2][64 * 64];
  __shared__ unsigned short Vs[2][64 * 64];
  __shared__ unsigned short Ps[4][16 * 64];

  const int tid  = threadIdx.x;
  const int lane = tid & 63;
  const int wave = tid >> 6;
  const int l15  = lane & 15;
  const int quad = lane >> 4;

  const int bh   = blockIdx.x & 31;   // inner -> XCD affinity (bh % 8)
  const int pair = blockIdx.x >> 5;   // 0..15

  const unsigned short* Qp = Qb  + (size_t)bh * PLANE;
  const unsigned short* Kp = Kb  + (size_t)bh * PLANE;
  const unsigned short* Vp = VTb + (size_t)bh * PLANE;

  const int swz = (((tid >> 3) ^ tid) & 7) * 8;
  const unsigned short* Kg = Kp + (size_t)(tid >> 3) * D_HEAD + swz;
  const unsigned short* Vg = Vp + (size_t)(tid >> 3) * T_SEQ + swz;
  unsigned short* myp = Ps[wave];
  const int b = bh >> 4, h = bh & 15;

  for (int ph = 0; ph < 2; ph++) {
    const int strip = ph ? (31 - pair) : pair;
    const int q0w   = strip * 64 + wave * 16;
    const int nch   = strip + 1;

    bf16x8 aq[2];
#pragma unroll
    for (int s = 0; s < 2; s++)
      aq[s] = *(const bf16x8*)(Qp + (size_t)(q0w + l15) * D_HEAD + 32 * s + quad * 8);

    float l_acc[4] = {};
    floatx4 o[4] = {};

    __syncthreads();
#pragma unroll
    for (int p = 0; p < 2; p++) {
      async_cp16((char*)Ks[0] + p * 4096 + wave * 1024, Kg + (size_t)(p * 32) * D_HEAD);
      async_cp16((char*)Vs[0] + p * 4096 + wave * 1024, Vg + (size_t)(p * 32) * T_SEQ);
    }

    for (int jc = 0; jc < nch; jc++) {
      __syncthreads();
      if (jc + 1 < nch) {
        const int j1 = (jc + 1) * 64;
        char* kd = (char*)Ks[(jc + 1) & 1];
        char* vd = (char*)Vs[(jc + 1) & 1];
#pragma unroll
        for (int p = 0; p < 2; p++) {
          async_cp16(kd + p * 4096 + wave * 1024, Kg + (size_t)(j1 + p * 32) * D_HEAD);
          async_cp16(vd + p * 4096 + wave * 1024, Vg + (size_t)(p * 32) * T_SEQ + j1);
        }
      }
      const char* Ksb = (const char*)Ks[jc & 1];
      const char* Vsb = (const char*)Vs[jc & 1];

      // S = Q K^T (exp2 domain)
      floatx4 s[4] = {};
#pragma unroll
      for (int t = 0; t < 4; t++)
#pragma unroll
        for (int ss = 0; ss < 2; ss++) {
          const int sa = ((ss * 4 + quad) ^ (l15 & 7)) * 16;
          bf16x8 bk = *(const bf16x8*)(Ksb + (16 * t + l15) * 128 + sa);
          s[t] = __builtin_amdgcn_mfma_f32_16x16x32_bf16(aq[ss], bk, s[t], 0, 0, 0);
        }

      if (jc == nch - 1) {
        const int j0 = jc * 64;
#pragma unroll
        for (int t = 0; t < 4; t++) {
          const int kk = j0 + 16 * t + l15;
#pragma unroll
          for (int r = 0; r < 4; r++)
            if (kk > q0w + quad * 4 + r) s[t][r] = -INFINITY;
        }
      }

      // fixed-bias softmax: p = exp2(s - SM_BIAS)
#pragma unroll
      for (int t = 0; t < 4; t++)
#pragma unroll
        for (int r = 0; r < 4; r++)
          s[t][r] = exp2f(s[t][r] - SM_BIAS);
#pragma unroll
      for (int r = 0; r < 4; r++)
        l_acc[r] += (s[0][r] + s[1][r]) + (s[2][r] + s[3][r]);

      // write P (swizzled) for A-operand readback
#pragma unroll
      for (int t = 0; t < 4; t++)
#pragma unroll
        for (int r = 0; r < 4; r++) {
          const int row  = quad * 4 + r;
          const int phys = ((2 * t + (l15 >> 3)) ^ (row & 7)) * 16;
          *(unsigned short*)((char*)myp + row * 128 + phys + (l15 & 7) * 2) =
              f32_to_bf16(s[t][r]);
        }
      asm volatile("s_waitcnt lgkmcnt(0)" ::: "memory");

      // O += P @ V
#pragma unroll
      for (int ks = 0; ks < 2; ks++) {
        const int pa = ((ks * 4 + quad) ^ (l15 & 7)) * 16;
        bf16x8 ap = *(const bf16x8*)((char*)myp + l15 * 128 + pa);
#pragma unroll
        for (int n = 0; n < 4; n++) {
          const int sa = ((ks * 4 + quad) ^ (l15 & 7)) * 16;
          bf16x8 bv = *(const bf16x8*)(Vsb + (16 * n + l15) * 128 + sa);
          o[n] = __builtin_amdgcn_mfma_f32_16x16x32_bf16(ap, bv, o[n], 0, 0, 0);
        }
      }
    }

    // per-strip l reduction
#pragma unroll
    for (int r = 0; r < 4; r++) {
#pragma unroll
      for (int d = 1; d < 16; d <<= 1) l_acc[r] += __shfl_xor(l_acc[r], d);
    }

#pragma unroll
    for (int r = 0; r < 4; r++) {
      const float inv_l = 1.0f / l_acc[r];
      const int t = q0w + quad * 4 + r;
#pragma unroll
      for (int n = 0; n < 4; n++)
        Out[(size_t)(b * T_SEQ + t) * D_MODEL + h * D_HEAD + 16 * n + l15] = o[n][r] * inv_l;
    }
  }
}

// ---------------------------------------------------------------------------
extern "C" void kernel_launch(void* const* d_in, const int* in_sizes, int n_in,
                              void* d_out, int out_size, void* d_ws, size_t ws_size,
                              hipStream_t stream) {
  const float* X  = (const float*)d_in[0];
  const float* Wq = (const float*)d_in[1];
  const float* Wk = (const float*)d_in[2];
  const float* Wv = (const float*)d_in[3];

  unsigned short* Qb = (unsigned short*)d_ws;
  unsigned short* Kb = Qb + (size_t)BATCH * N_HEADS * T_SEQ * D_HEAD;
  unsigned short* VT = Kb + (size_t)BATCH * N_HEADS * T_SEQ * D_HEAD;

  unsigned short* Xb = (unsigned short*)d_out;   // scratch, overwritten by attn
  unsigned short* Wb = Xb + (size_t)NX;

  cvt_kernel<<<3584, 256, 0, stream>>>(X, Wq, Wk, Wv, Xb, Wb);

  dim3 g1(N_TOT / 128, M_TOT / 128);
  gemm_qkv<<<g1, 256, 0, stream>>>(Xb, Wb, Qb, Kb, VT);

  attn_kernel<<<512, 256, 0, stream>>>(Qb, Kb, VT, (float*)d_out);
}

// Round 11
// 161.523 us; speedup vs baseline: 1.1065x; 1.0337x over previous
//
#include <hip/hip_runtime.h>

// B=2, T=2048, D_MODEL=1024, H=16, Dh=64. Inputs fp32, output fp32.
// R11: attn grid 512 -> 1024 single-strip blocks (4 blocks/CU residency),
//      heavy-first (strip = 31 - blockIdx>>5), bh kept inner (XCD affinity,
//      verified by R10's FETCH 120->12 MB). gemm/cvt unchanged from R10.

using bf16x8  = __attribute__((ext_vector_type(8))) __bf16;
using floatx4 = __attribute__((ext_vector_type(4))) float;

#define T_SEQ   2048
#define D_MODEL 1024
#define N_HEADS 16
#define D_HEAD  64
#define BATCH   2
#define M_TOT   4096
#define N_TOT   3072
#define PLANE   (T_SEQ * D_HEAD)
#define NX      (M_TOT * D_MODEL)
#define NWSEG   (D_MODEL * D_MODEL)
#define QSCALE  0.18033688f   // 0.125 * log2(e)
#define SM_BIAS 24.0f

__device__ __forceinline__ unsigned short f32_to_bf16(float f) {
  unsigned int u = __float_as_uint(f);
  u += 0x7fffu + ((u >> 16) & 1u);
  return (unsigned short)(u >> 16);
}
__device__ __forceinline__ unsigned int pack2_bf16(float a, float b) {
  unsigned int ua = __float_as_uint(a) + 0x8000u;
  unsigned int ub = __float_as_uint(b) + 0x8000u;
  return __builtin_amdgcn_perm(ub, ua, 0x07060302);
}
__device__ __forceinline__ void async_cp16(void* lds, const void* gptr) {
  __builtin_amdgcn_global_load_lds(
      (const __attribute__((address_space(1))) unsigned int*)gptr,
      (__attribute__((address_space(3))) unsigned int*)lds, 16, 0, 0);
}

// ---------------------------------------------------------------------------
// K0: fp32 -> bf16 cvt.
// ---------------------------------------------------------------------------
__global__ __launch_bounds__(256) void cvt_kernel(
    const float* __restrict__ X,  const float* __restrict__ Wq,
    const float* __restrict__ Wk, const float* __restrict__ Wv,
    unsigned short* __restrict__ Xb, unsigned short* __restrict__ Wb)
{
  const size_t i = ((size_t)blockIdx.x * 256 + threadIdx.x) * 8;
  const float* src;
  unsigned short* dst;
  if (i < NX) { src = X + i; dst = Xb + i; }
  else {
    const size_t r = i - NX;
    const int w = (int)(r >> 20);
    const size_t o = r & (NWSEG - 1);
    src = ((w == 0) ? Wq : (w == 1) ? Wk : Wv) + o;
    dst = Wb + r;
  }
  float4 f0 = *(const float4*)src;
  float4 f1 = *(const float4*)(src + 4);
  uint4 out;
  out.x = pack2_bf16(f0.x, f0.y);
  out.y = pack2_bf16(f0.z, f0.w);
  out.z = pack2_bf16(f1.x, f1.y);
  out.w = pack2_bf16(f1.z, f1.w);
  *(uint4*)dst = out;
}

// ---------------------------------------------------------------------------
// K1: bf16 GEMM C[4096x3072] = Xb @ Wb^T. Grid (24,32), block 256. BK=64.
// Single-buffered 32KB LDS (cross-block overlap at ~3 blocks/CU).
// ---------------------------------------------------------------------------
__global__ __launch_bounds__(256) void gemm_qkv(
    const unsigned short* __restrict__ Xb,
    const unsigned short* __restrict__ Wb,
    unsigned short* __restrict__ Qb,         // [B][H][T][64] * QSCALE
    unsigned short* __restrict__ Kb,         // [B][H][T][64]
    unsigned short* __restrict__ VTb)        // [B][H][64][T]
{
  __shared__ unsigned short Als[128 * 64];
  __shared__ unsigned short Bls[128 * 64];

  const int tid  = threadIdx.x;
  const int lane = tid & 63;
  const int wave = tid >> 6;
  const int l15  = lane & 15;
  const int quad = lane >> 4;
  const int wm   = wave >> 1, wn = wave & 1;

  const int n_blk = blockIdx.x * 128;
  const int m_blk = blockIdx.y * 128;

  const int swz = (((tid >> 3) ^ tid) & 7) * 8;
  const unsigned short* Ag = Xb + (size_t)(m_blk + (tid >> 3)) * D_MODEL + swz;
  const unsigned short* Bg = Wb + (size_t)(n_blk + (tid >> 3)) * D_MODEL + swz;
  char* Alds = (char*)Als + wave * 1024;
  char* Blds = (char*)Bls + wave * 1024;

  floatx4 acc[4][4] = {};

  for (int k0 = 0; k0 < D_MODEL; k0 += 64) {
    __syncthreads();
#pragma unroll
    for (int p = 0; p < 4; p++) {
      async_cp16(Alds + p * 4096, Ag + (size_t)p * 32 * D_MODEL + k0);
      async_cp16(Blds + p * 4096, Bg + (size_t)p * 32 * D_MODEL + k0);
    }
    __syncthreads();

#pragma unroll
    for (int ks = 0; ks < 2; ks++) {
      bf16x8 a[4], b[4];
#pragma unroll
      for (int i = 0; i < 4; i++) {
        const int sa = ((ks * 4 + quad) ^ (l15 & 7)) * 16;
        a[i] = *(const bf16x8*)((char*)Als + (wm * 64 + 16 * i + l15) * 128 + sa);
        b[i] = *(const bf16x8*)((char*)Bls + (wn * 64 + 16 * i + l15) * 128 + sa);
      }
#pragma unroll
      for (int mi = 0; mi < 4; mi++)
#pragma unroll
        for (int ni = 0; ni < 4; ni++)
          acc[mi][ni] = __builtin_amdgcn_mfma_f32_16x16x32_bf16(a[mi], b[ni], acc[mi][ni], 0, 0, 0);
    }
  }

  // epilogue: stage 64x64 C tile in LDS (swizzled), coalesced copy-out
  __syncthreads();
  char* ep = (char*)Als + wave * 8192;
  const int w_sel  = n_blk >> 10;
  const int m_base = m_blk + wm * 64;
  const int n_base = n_blk + wn * 64;
  const int h      = (n_base & 1023) >> 6;
  const float csc  = (w_sel == 0) ? QSCALE : 1.0f;

  if (w_sel < 2) {
#pragma unroll
    for (int mi = 0; mi < 4; mi++)
#pragma unroll
      for (int ni = 0; ni < 4; ni++)
#pragma unroll
        for (int r = 0; r < 4; r++) {
          const int row  = 16 * mi + quad * 4 + r;
          const int colb = (16 * ni + l15) * 2;
          const int phys = ((colb >> 4) ^ (row & 7)) * 16;
          *(unsigned short*)(ep + row * 128 + phys + (colb & 15)) =
              f32_to_bf16(acc[mi][ni][r] * csc);
        }
  } else {
#pragma unroll
    for (int mi = 0; mi < 4; mi++)
#pragma unroll
      for (int ni = 0; ni < 4; ni++)
#pragma unroll
        for (int r = 0; r < 4; r++) {
          const int row  = 16 * ni + l15;
          const int colb = (16 * mi + quad * 4 + r) * 2;
          const int phys = ((colb >> 4) ^ (row & 7)) * 16;
          *(unsigned short*)(ep + row * 128 + phys + (colb & 15)) =
              f32_to_bf16(acc[mi][ni][r]);
        }
  }
  asm volatile("s_waitcnt lgkmcnt(0)" ::: "memory");

#pragma unroll
  for (int pass = 0; pass < 8; pass++) {
    const int row  = pass * 8 + (lane >> 3);
    const int phys = ((lane & 7) ^ (row & 7)) * 16;
    uint4 v = *(const uint4*)(ep + row * 128 + phys);
    if (w_sel < 2) {
      const int m  = m_base + row;
      const int bb = m >> 11;
      const int t  = m & (T_SEQ - 1);
      unsigned short* dst = ((w_sel == 0) ? Qb : Kb) +
          ((size_t)(bb * N_HEADS + h) * T_SEQ + t) * D_HEAD + (lane & 7) * 8;
      *(uint4*)dst = v;
    } else {
      const int bb = m_base >> 11;
      unsigned short* dst = VTb +
          ((size_t)(bb * N_HEADS + h) * D_HEAD + row) * T_SEQ + (m_base & (T_SEQ - 1)) + (lane & 7) * 8;
      *(uint4*)dst = v;
    }
  }
}

// ---------------------------------------------------------------------------
// K2: causal flash attention, fixed-max softmax.
// Grid 1024: bh = blockIdx & 31 (XCD = bh%8), strip = 31 - (blockIdx >> 5)
// (heavy strips dispatch first). Block 256 = 4 waves x 16q = one 64q strip.
// ---------------------------------------------------------------------------
__global__ __launch_bounds__(256) void attn_kernel(
    const unsigned short* __restrict__ Qb,   // pre-scaled by QSCALE
    const unsigned short* __restrict__ Kb,
    const unsigned short* __restrict__ VTb,
    float* __restrict__ Out)
{
  __shared__ unsigned short Ks[2][64 * 64];
  __shared__ unsigned short Vs[2][64 * 64];
  __shared__ unsigned short Ps[4][16 * 64];

  const int tid  = threadIdx.x;
  const int lane = tid & 63;
  const int wave = tid >> 6;
  const int l15  = lane & 15;
  const int quad = lane >> 4;

  const int bh    = blockIdx.x & 31;        // inner -> XCD affinity (bh % 8)
  const int strip = 31 - (blockIdx.x >> 5); // heavy-first
  const int q0w   = strip * 64 + wave * 16;
  const int nch   = strip + 1;

  const unsigned short* Qp = Qb  + (size_t)bh * PLANE;
  const unsigned short* Kp = Kb  + (size_t)bh * PLANE;
  const unsigned short* Vp = VTb + (size_t)bh * PLANE;

  const int swz = (((tid >> 3) ^ tid) & 7) * 8;
  const unsigned short* Kg = Kp + (size_t)(tid >> 3) * D_HEAD + swz;
  const unsigned short* Vg = Vp + (size_t)(tid >> 3) * T_SEQ + swz;
  unsigned short* myp = Ps[wave];
  const int b = bh >> 4, h = bh & 15;

  bf16x8 aq[2];
#pragma unroll
  for (int s = 0; s < 2; s++)
    aq[s] = *(const bf16x8*)(Qp + (size_t)(q0w + l15) * D_HEAD + 32 * s + quad * 8);

  float l_acc[4] = {};
  floatx4 o[4] = {};

  // prologue: stage chunk 0 -> buf 0
#pragma unroll
  for (int p = 0; p < 2; p++) {
    async_cp16((char*)Ks[0] + p * 4096 + wave * 1024, Kg + (size_t)(p * 32) * D_HEAD);
    async_cp16((char*)Vs[0] + p * 4096 + wave * 1024, Vg + (size_t)(p * 32) * T_SEQ);
  }

  for (int jc = 0; jc < nch; jc++) {
    __syncthreads();
    if (jc + 1 < nch) {
      const int j1 = (jc + 1) * 64;
      char* kd = (char*)Ks[(jc + 1) & 1];
      char* vd = (char*)Vs[(jc + 1) & 1];
#pragma unroll
      for (int p = 0; p < 2; p++) {
        async_cp16(kd + p * 4096 + wave * 1024, Kg + (size_t)(j1 + p * 32) * D_HEAD);
        async_cp16(vd + p * 4096 + wave * 1024, Vg + (size_t)(p * 32) * T_SEQ + j1);
      }
    }
    const char* Ksb = (const char*)Ks[jc & 1];
    const char* Vsb = (const char*)Vs[jc & 1];

    // S = Q K^T (exp2 domain)
    floatx4 s[4] = {};
#pragma unroll
    for (int t = 0; t < 4; t++)
#pragma unroll
      for (int ss = 0; ss < 2; ss++) {
        const int sa = ((ss * 4 + quad) ^ (l15 & 7)) * 16;
        bf16x8 bk = *(const bf16x8*)(Ksb + (16 * t + l15) * 128 + sa);
        s[t] = __builtin_amdgcn_mfma_f32_16x16x32_bf16(aq[ss], bk, s[t], 0, 0, 0);
      }

    if (jc == nch - 1) {   // diagonal chunk
      const int j0 = jc * 64;
#pragma unroll
      for (int t = 0; t < 4; t++) {
        const int kk = j0 + 16 * t + l15;
#pragma unroll
        for (int r = 0; r < 4; r++)
          if (kk > q0w + quad * 4 + r) s[t][r] = -INFINITY;
      }
    }

    // fixed-bias softmax: p = exp2(s - SM_BIAS)
#pragma unroll
    for (int t = 0; t < 4; t++)
#pragma unroll
      for (int r = 0; r < 4; r++)
        s[t][r] = exp2f(s[t][r] - SM_BIAS);
#pragma unroll
    for (int r = 0; r < 4; r++)
      l_acc[r] += (s[0][r] + s[1][r]) + (s[2][r] + s[3][r]);

    // write P (swizzled) for A-operand readback
#pragma unroll
    for (int t = 0; t < 4; t++)
#pragma unroll
      for (int r = 0; r < 4; r++) {
        const int row  = quad * 4 + r;
        const int phys = ((2 * t + (l15 >> 3)) ^ (row & 7)) * 16;
        *(unsigned short*)((char*)myp + row * 128 + phys + (l15 & 7) * 2) =
            f32_to_bf16(s[t][r]);
      }
    asm volatile("s_waitcnt lgkmcnt(0)" ::: "memory");

    // O += P @ V
#pragma unroll
    for (int ks = 0; ks < 2; ks++) {
      const int pa = ((ks * 4 + quad) ^ (l15 & 7)) * 16;
      bf16x8 ap = *(const bf16x8*)((char*)myp + l15 * 128 + pa);
#pragma unroll
      for (int n = 0; n < 4; n++) {
        const int sa = ((ks * 4 + quad) ^ (l15 & 7)) * 16;
        bf16x8 bv = *(const bf16x8*)(Vsb + (16 * n + l15) * 128 + sa);
        o[n] = __builtin_amdgcn_mfma_f32_16x16x32_bf16(ap, bv, o[n], 0, 0, 0);
      }
    }
  }

  // per-strip l reduction
#pragma unroll
  for (int r = 0; r < 4; r++) {
#pragma unroll
    for (int d = 1; d < 16; d <<= 1) l_acc[r] += __shfl_xor(l_acc[r], d);
  }

#pragma unroll
  for (int r = 0; r < 4; r++) {
    const float inv_l = 1.0f / l_acc[r];
    const int t = q0w + quad * 4 + r;
#pragma unroll
    for (int n = 0; n < 4; n++)
      Out[(size_t)(b * T_SEQ + t) * D_MODEL + h * D_HEAD + 16 * n + l15] = o[n][r] * inv_l;
  }
}

// ---------------------------------------------------------------------------
extern "C" void kernel_launch(void* const* d_in, const int* in_sizes, int n_in,
                              void* d_out, int out_size, void* d_ws, size_t ws_size,
                              hipStream_t stream) {
  const float* X  = (const float*)d_in[0];
  const float* Wq = (const float*)d_in[1];
  const float* Wk = (const float*)d_in[2];
  const float* Wv = (const float*)d_in[3];

  unsigned short* Qb = (unsigned short*)d_ws;
  unsigned short* Kb = Qb + (size_t)BATCH * N_HEADS * T_SEQ * D_HEAD;
  unsigned short* VT = Kb + (size_t)BATCH * N_HEADS * T_SEQ * D_HEAD;

  unsigned short* Xb = (unsigned short*)d_out;   // scratch, overwritten by attn
  unsigned short* Wb = Xb + (size_t)NX;

  cvt_kernel<<<3584, 256, 0, stream>>>(X, Wq, Wk, Wv, Xb, Wb);

  dim3 g1(N_TOT / 128, M_TOT / 128);
  gemm_qkv<<<g1, 256, 0, stream>>>(Xb, Wb, Qb, Kb, VT);

  attn_kernel<<<1024, 256, 0, stream>>>(Qb, Kb, VT, (float*)d_out);
}